// Round 1
// baseline (495.765 us; speedup 1.0000x reference)
//
#include <hip/hip_runtime.h>

// ManifoldNetSPD SPD identity-pad:
//   x: [8,16,256,256,3,3] f32  ->  out: [8,16,258,258,3,3] f32
//   border cells (i or j on the 1-wide pad ring) = eye(3), interior = copy.
//
// Pure memory-bound copy. Interior row (b,c,i) is a 2304-float contiguous
// copy (256 cells * 9 floats) from a 2304-float contiguous source row.
// src rows are 16B-aligned; dst rows are 4B-aligned (offset 9 floats == 1 mod 4)
// -- CDNA global dwordx4 needs only dword alignment, so float4 on both is fine.

constexpr int B  = 8;
constexpr int C  = 16;
constexpr int H  = 256;
constexpr int W  = 256;
constexpr int HP = 258;   // H + 2
constexpr int WP = 258;   // W + 2

constexpr int       IMGS    = B * C;                        // 128
constexpr long long ROW_IN  = (long long)W * 9;             // 2304 floats
constexpr long long IMG_IN  = (long long)H * ROW_IN;
constexpr long long ROW_OUT = (long long)WP * 9;            // 2322 floats
constexpr long long IMG_OUT = (long long)HP * ROW_OUT;      // 599076 floats

constexpr int COPY_BLOCKS   = IMGS * H;                     // 32768: one per interior row
constexpr int BORDER_BLOCKS = 2048;
// border cells per image: top 258 + bottom 258 + left 256 + right 256 = 1028
constexpr int       CELLS_PER_IMG = 2 * WP + 2 * H;         // 1028
constexpr long long BORDER_FLOATS = (long long)IMGS * CELLS_PER_IMG * 9; // 1,184,256

__global__ __launch_bounds__(192) void spd_pad_kernel(const float* __restrict__ x,
                                                      float* __restrict__ out) {
    const int blk = blockIdx.x;
    const int tid = threadIdx.x;  // 0..191 (3 waves)

    if (blk < COPY_BLOCKS) {
        // ---- interior row copy: 576 float4 per row, 192 threads x 3 ----
        const int img = blk >> 8;          // blk / 256
        const int i   = blk & 255;         // source row; dest row = i+1
        const float4* __restrict__ src =
            reinterpret_cast<const float4*>(x + (long long)img * IMG_IN + (long long)i * ROW_IN);
        float4* __restrict__ dst =
            reinterpret_cast<float4*>(out + (long long)img * IMG_OUT + (long long)(i + 1) * ROW_OUT + 9);
#pragma unroll
        for (int k = 0; k < 3; ++k) {
            const int idx = tid + k * 192;
            dst[idx] = src[idx];
        }
    } else {
        // ---- border fill: grid-stride over 1,184,256 eye-pattern floats ----
        const long long stride = (long long)BORDER_BLOCKS * 192;
        long long t = (long long)(blk - COPY_BLOCKS) * 192 + tid;
        for (; t < BORDER_FLOATS; t += stride) {
            const int       e    = (int)(t % 9);            // element within 3x3 cell
            const long long cell = t / 9;
            const int       k    = (int)(cell % CELLS_PER_IMG);
            const int       img  = (int)(cell / CELLS_PER_IMG);
            int i, j;
            if (k < WP) {                 // top row
                i = 0;       j = k;
            } else if (k < 2 * WP) {      // bottom row
                i = HP - 1;  j = k - WP;
            } else if (k < 2 * WP + H) {  // left column, interior rows
                j = 0;       i = k - 2 * WP + 1;
            } else {                      // right column, interior rows
                j = WP - 1;  i = k - (2 * WP + H) + 1;
            }
            const float v = (e == 0 || e == 4 || e == 8) ? 1.0f : 0.0f;
            out[(long long)img * IMG_OUT + (long long)i * ROW_OUT + (long long)j * 9 + e] = v;
        }
    }
}

extern "C" void kernel_launch(void* const* d_in, const int* in_sizes, int n_in,
                              void* d_out, int out_size, void* d_ws, size_t ws_size,
                              hipStream_t stream) {
    const float* x   = (const float*)d_in[0];
    float*       out = (float*)d_out;
    // d_in[1] is padding_dim (==1), baked into the constants above.
    spd_pad_kernel<<<dim3(COPY_BLOCKS + BORDER_BLOCKS), dim3(192), 0, stream>>>(x, out);
}